// Round 5
// baseline (477.391 us; speedup 1.0000x reference)
//
#include <hip/hip_runtime.h>
#include <math.h>

#define N_NODES 50000
#define N_EDGES 800000
#define F_IN    64
#define H_DIM   128
#define N_GRAPH 512
#define NEG_SLOPE 0.2f
#define SCAN_NB ((N_NODES + 255) / 256)   // 196

// ---------------------------------------------------------------- CSR build
__global__ __launch_bounds__(256) void k_hist(const int* __restrict__ dst,
                                              int* __restrict__ counts) {
    int e = blockIdx.x * 256 + threadIdx.x;
    if (e < N_EDGES) atomicAdd(&counts[dst[e]], 1);
}

// Single-dispatch exclusive scan over counts -> offsets/cursor,
// decoupled-lookback style. status[b]: 0 = invalid,
// bit30|aggregate, bit31|inclusive-prefix (values < 2^30).
__global__ __launch_bounds__(256) void k_scan(const int* __restrict__ counts,
                                              int* __restrict__ offsets,
                                              int* __restrict__ cursor,
                                              unsigned int* __restrict__ status) {
    __shared__ int s[256];
    __shared__ int sbase;
    const int t = threadIdx.x, b = blockIdx.x;
    const int gid = b * 256 + t;
    int v = (gid < N_NODES) ? counts[gid] : 0;
    s[t] = v;
    __syncthreads();
    for (int off = 1; off < 256; off <<= 1) {
        int x = (t >= off) ? s[t - off] : 0;
        __syncthreads();
        s[t] += x;
        __syncthreads();
    }
    int incl = s[t];
    int total = s[255];
    if (t == 0) {
        int run = 0;
        if (b == 0) {
            __threadfence();
            atomicExch(&status[0], 0x80000000u | (unsigned)total);
        } else {
            __threadfence();
            atomicExch(&status[b], 0x40000000u | (unsigned)total);
            int j = b - 1;
            while (true) {
                unsigned st = atomicAdd(&status[j], 0u);
                if (st & 0x80000000u) { run += (int)(st & 0x3FFFFFFFu); break; }
                if (st & 0x40000000u) { run += (int)(st & 0x3FFFFFFFu); --j; }
            }
            __threadfence();
            atomicExch(&status[b], 0x80000000u | (unsigned)(run + total));
        }
        sbase = run;
    }
    __syncthreads();
    int base = sbase;
    if (gid < N_NODES) {
        int e = base + incl - v;
        offsets[gid] = e;
        cursor[gid]  = e;
    }
    if (gid == N_NODES) offsets[N_NODES] = N_EDGES;
}

__global__ __launch_bounds__(256) void k_fill(const int* __restrict__ src,
                                              const int* __restrict__ dst,
                                              int* __restrict__ cursor,
                                              int* __restrict__ col_src) {
    int e = blockIdx.x * 256 + threadIdx.x;
    if (e < N_EDGES) {
        int pos = atomicAdd(&cursor[dst[e]], 1);
        col_src[pos] = src[e];
    }
}

// ---------------------------------------------------------------- dual GEMM
// C = X @ W + b for W in {Wl, Wr} chosen by blockIdx.y.  X: N x K, W: K x 128.
#define XPITCH 132
__global__ __launch_bounds__(256) void k_gemm_dual(
    const float* __restrict__ X,
    const float* __restrict__ Wl, const float* __restrict__ bl,
    const float* __restrict__ Wr, const float* __restrict__ br,
    float* __restrict__ OL, float* __restrict__ OR_, int K)
{
    const float* W  = blockIdx.y ? Wr : Wl;
    const float* bs = blockIdx.y ? br : bl;
    float*       O  = blockIdx.y ? OR_ : OL;

    __shared__ float XsT[32 * XPITCH];
    __shared__ float Ws[32 * 128];

    const int tid = threadIdx.x;
    const int tx = tid & 15;
    const int ty = tid >> 4;
    const int row0 = blockIdx.x * 128;

    float acc[8][8];
#pragma unroll
    for (int i = 0; i < 8; ++i)
#pragma unroll
        for (int j = 0; j < 8; ++j) acc[i][j] = 0.f;

    for (int kk = 0; kk < K; kk += 32) {
#pragma unroll
        for (int jj = 0; jj < 4; ++jj) {
            int j = tid + jj * 256;
            int r = j >> 3;
            int c4 = (j & 7) << 2;
            int grow = row0 + r;
            float4 v = make_float4(0.f, 0.f, 0.f, 0.f);
            if (grow < N_NODES)
                v = *(const float4*)(X + (size_t)grow * K + kk + c4);
            XsT[(c4 + 0) * XPITCH + r] = v.x;
            XsT[(c4 + 1) * XPITCH + r] = v.y;
            XsT[(c4 + 2) * XPITCH + r] = v.z;
            XsT[(c4 + 3) * XPITCH + r] = v.w;
        }
#pragma unroll
        for (int jj = 0; jj < 4; ++jj) {
            int j = tid + jj * 256;
            int r = j >> 5;
            int c4 = (j & 31) << 2;
            float4 v = *(const float4*)(W + (size_t)(kk + r) * 128 + c4);
            *(float4*)(Ws + r * 128 + c4) = v;
        }
        __syncthreads();
#pragma unroll 8
        for (int k = 0; k < 32; ++k) {
            float4 a0 = *(const float4*)(XsT + k * XPITCH + ty * 8);
            float4 a1 = *(const float4*)(XsT + k * XPITCH + ty * 8 + 4);
            float4 b0 = *(const float4*)(Ws + k * 128 + tx * 4);
            float4 b1 = *(const float4*)(Ws + k * 128 + 64 + tx * 4);
            float a_[8] = {a0.x, a0.y, a0.z, a0.w, a1.x, a1.y, a1.z, a1.w};
            float b_[8] = {b0.x, b0.y, b0.z, b0.w, b1.x, b1.y, b1.z, b1.w};
#pragma unroll
            for (int i = 0; i < 8; ++i)
#pragma unroll
                for (int j = 0; j < 8; ++j)
                    acc[i][j] = fmaf(a_[i], b_[j], acc[i][j]);
        }
        __syncthreads();
    }

    const float4 bb0 = *(const float4*)(bs + tx * 4);
    const float4 bb1 = *(const float4*)(bs + 64 + tx * 4);
#pragma unroll
    for (int i = 0; i < 8; ++i) {
        int grow = row0 + ty * 8 + i;
        if (grow < N_NODES) {
            float4 o0, o1;
            o0.x = acc[i][0] + bb0.x; o0.y = acc[i][1] + bb0.y;
            o0.z = acc[i][2] + bb0.z; o0.w = acc[i][3] + bb0.w;
            o1.x = acc[i][4] + bb1.x; o1.y = acc[i][5] + bb1.y;
            o1.z = acc[i][6] + bb1.z; o1.w = acc[i][7] + bb1.w;
            *(float4*)(O + (size_t)grow * 128 + tx * 4)      = o0;
            *(float4*)(O + (size_t)grow * 128 + 64 + tx * 4) = o1;
        }
    }
}

// ---------------------------------------------------------------- edge phase
__device__ __forceinline__ float dot8_leaky(const float4& x0, const float4& x1,
                                            const float4& r0, const float4& r1,
                                            const float4& a0, const float4& a1) {
    float s = 0.f, e;
    e = x0.x + r0.x; s = fmaf(a0.x, (e > 0.f ? e : NEG_SLOPE * e), s);
    e = x0.y + r0.y; s = fmaf(a0.y, (e > 0.f ? e : NEG_SLOPE * e), s);
    e = x0.z + r0.z; s = fmaf(a0.z, (e > 0.f ? e : NEG_SLOPE * e), s);
    e = x0.w + r0.w; s = fmaf(a0.w, (e > 0.f ? e : NEG_SLOPE * e), s);
    e = x1.x + r1.x; s = fmaf(a1.x, (e > 0.f ? e : NEG_SLOPE * e), s);
    e = x1.y + r1.y; s = fmaf(a1.y, (e > 0.f ? e : NEG_SLOPE * e), s);
    e = x1.z + r1.z; s = fmaf(a1.z, (e > 0.f ? e : NEG_SLOPE * e), s);
    e = x1.w + r1.w; s = fmaf(a1.w, (e > 0.f ? e : NEG_SLOPE * e), s);
    return s;
}

// Two waves per destination node (8 groups of 16 lanes), online softmax.
// Group g8 = wave*4 + quarter handles edges ibeg+g8, step 8. Intra-wave
// merge via shfl_xor(16/32); inter-wave merge via LDS.
__global__ __launch_bounds__(256) void k_edge(
    const float* __restrict__ xl, const float* __restrict__ xr,
    const float* __restrict__ att, const float* __restrict__ bias,
    const int* __restrict__ offsets, const int* __restrict__ col_src,
    float* __restrict__ out)
{
    __shared__ float  ms[2][16], ls[2][16];
    __shared__ float4 a0s[2][16], a1s[2][16];

    const int tid  = threadIdx.x;
    const int nd   = tid >> 7;                 // node within block (0/1)
    const int d    = blockIdx.x * 2 + nd;      // N_NODES even -> always valid
    const int wv   = (tid >> 6) & 1;           // wave within node
    const int lane = tid & 63;
    const int q    = lane >> 4;
    const int t    = lane & 15;
    const int g8   = wv * 4 + q;
    const size_t dim0 = (size_t)t * 8;

    const float4 r0 = *(const float4*)(xr + (size_t)d * 128 + dim0);
    const float4 r1 = *(const float4*)(xr + (size_t)d * 128 + dim0 + 4);
    const float4 a0 = *(const float4*)(att + dim0);
    const float4 a1 = *(const float4*)(att + dim0 + 4);

    float m = -INFINITY, lsum = 0.f;
    float4 acc0 = make_float4(0.f, 0.f, 0.f, 0.f);
    float4 acc1 = make_float4(0.f, 0.f, 0.f, 0.f);

    if (wv == 0) {  // self edge handled by wave 0, quarter 0
        const float4 xs0 = *(const float4*)(xl + (size_t)d * 128 + dim0);
        const float4 xs1 = *(const float4*)(xl + (size_t)d * 128 + dim0 + 4);
        float slf = dot8_leaky(xs0, xs1, r0, r1, a0, a1);
#pragma unroll
        for (int off = 1; off < 16; off <<= 1) slf += __shfl_xor(slf, off);
        if (q == 0) { m = slf; lsum = 1.f; acc0 = xs0; acc1 = xs1; }
    }

    const int ibeg = offsets[d], iend = offsets[d + 1];
    for (int i = ibeg + g8; i < iend; i += 8) {
        int s = col_src[i];
        const float4 x0 = *(const float4*)(xl + (size_t)s * 128 + dim0);
        const float4 x1 = *(const float4*)(xl + (size_t)s * 128 + dim0 + 4);
        float logit = dot8_leaky(x0, x1, r0, r1, a0, a1);
#pragma unroll
        for (int off = 1; off < 16; off <<= 1) logit += __shfl_xor(logit, off);
        float nm = fmaxf(m, logit);
        float sc = __expf(m - nm);       // m may be -inf -> 0 (nm finite)
        float w  = __expf(logit - nm);
        lsum = lsum * sc + w;
        acc0.x = acc0.x * sc + w * x0.x;
        acc0.y = acc0.y * sc + w * x0.y;
        acc0.z = acc0.z * sc + w * x0.z;
        acc0.w = acc0.w * sc + w * x0.w;
        acc1.x = acc1.x * sc + w * x1.x;
        acc1.y = acc1.y * sc + w * x1.y;
        acc1.z = acc1.z * sc + w * x1.z;
        acc1.w = acc1.w * sc + w * x1.w;
        m = nm;
    }

    // intra-wave merge of the 4 quarters
    float M = m;
    M = fmaxf(M, __shfl_xor(M, 16));
    M = fmaxf(M, __shfl_xor(M, 32));
    // fmaxf(nan,-88) = -88 handles the all-(-inf) wave (wave 1, low degree)
    float sc = __expf(fmaxf(m - M, -88.f));
    lsum *= sc;
    acc0.x *= sc; acc0.y *= sc; acc0.z *= sc; acc0.w *= sc;
    acc1.x *= sc; acc1.y *= sc; acc1.z *= sc; acc1.w *= sc;
#pragma unroll
    for (int off = 16; off <= 32; off <<= 1) {
        lsum  += __shfl_xor(lsum, off);
        acc0.x += __shfl_xor(acc0.x, off);
        acc0.y += __shfl_xor(acc0.y, off);
        acc0.z += __shfl_xor(acc0.z, off);
        acc0.w += __shfl_xor(acc0.w, off);
        acc1.x += __shfl_xor(acc1.x, off);
        acc1.y += __shfl_xor(acc1.y, off);
        acc1.z += __shfl_xor(acc1.z, off);
        acc1.w += __shfl_xor(acc1.w, off);
    }
    m = M;

    // inter-wave merge via LDS
    if (wv == 1 && q == 0) {
        ms[nd][t] = m; ls[nd][t] = lsum;
        a0s[nd][t] = acc0; a1s[nd][t] = acc1;
    }
    __syncthreads();
    if (wv == 0 && q == 0) {
        float m1 = ms[nd][t], l1 = ls[nd][t];
        float4 c0 = a0s[nd][t], c1 = a1s[nd][t];
        float Mg = fmaxf(m, m1);
        float s0 = __expf(fmaxf(m  - Mg, -88.f));
        float s1 = __expf(fmaxf(m1 - Mg, -88.f));
        lsum = lsum * s0 + l1 * s1;
        acc0.x = acc0.x * s0 + c0.x * s1;
        acc0.y = acc0.y * s0 + c0.y * s1;
        acc0.z = acc0.z * s0 + c0.z * s1;
        acc0.w = acc0.w * s0 + c0.w * s1;
        acc1.x = acc1.x * s0 + c1.x * s1;
        acc1.y = acc1.y * s0 + c1.y * s1;
        acc1.z = acc1.z * s0 + c1.z * s1;
        acc1.w = acc1.w * s0 + c1.w * s1;

        float inv = 1.f / lsum;
        const float4 b0 = *(const float4*)(bias + dim0);
        const float4 b1 = *(const float4*)(bias + dim0 + 4);
        float4 o0, o1;
        o0.x = fmaxf(fmaf(acc0.x, inv, b0.x), 0.f);
        o0.y = fmaxf(fmaf(acc0.y, inv, b0.y), 0.f);
        o0.z = fmaxf(fmaf(acc0.z, inv, b0.z), 0.f);
        o0.w = fmaxf(fmaf(acc0.w, inv, b0.w), 0.f);
        o1.x = fmaxf(fmaf(acc1.x, inv, b1.x), 0.f);
        o1.y = fmaxf(fmaf(acc1.y, inv, b1.y), 0.f);
        o1.z = fmaxf(fmaf(acc1.z, inv, b1.z), 0.f);
        o1.w = fmaxf(fmaf(acc1.w, inv, b1.w), 0.f);
        *(float4*)(out + (size_t)d * 128 + dim0)     = o0;
        *(float4*)(out + (size_t)d * 128 + dim0 + 4) = o1;
    }
}

// ---------------------------------------------------------------- pool+head
__global__ __launch_bounds__(128) void k_pool_head(
    const float* __restrict__ h, const int* __restrict__ batch,
    float* __restrict__ psum, float* __restrict__ pcnt,
    int* __restrict__ done,
    const float* __restrict__ Wlin, const float* __restrict__ blin,
    float* __restrict__ out)
{
    int dim = threadIdx.x;
    int n0 = blockIdx.x * 128;
    int nend = n0 + 128; if (nend > N_NODES) nend = N_NODES;
    float accv = 0.f;
    int cur = -1, crun = 0;
    for (int n = n0; n < nend; ++n) {
        int g = batch[n];
        if (g != cur) {
            if (cur >= 0) {
                atomicAdd(&psum[cur * 128 + dim], accv);
                if (dim == 0) atomicAdd(&pcnt[cur], (float)crun);
            }
            cur = g; accv = 0.f; crun = 0;
        }
        accv += h[(size_t)n * 128 + dim];
        crun++;
    }
    if (cur >= 0) {
        atomicAdd(&psum[cur * 128 + dim], accv);
        if (dim == 0) atomicAdd(&pcnt[cur], (float)crun);
    }

    // last block computes the head
    __threadfence();
    __shared__ int lastFlag;
    if (threadIdx.x == 0) {
        int dn = atomicAdd(done, 1);
        lastFlag = (dn == (int)gridDim.x - 1);
    }
    __syncthreads();
    if (lastFlag) {
        __threadfence();
        int t = threadIdx.x;
        for (int g = t; g < N_GRAPH; g += 128) {
            float c = fmaxf(pcnt[g], 1.f);
            float acc = 0.f;
#pragma unroll 8
            for (int k = 0; k < 128; ++k)
                acc = fmaf(psum[g * 128 + k], Wlin[k], acc);
            out[g] = acc / c + blin[0];
        }
    }
}

// ---------------------------------------------------------------- launch
extern "C" void kernel_launch(void* const* d_in, const int* in_sizes, int n_in,
                              void* d_out, int out_size, void* d_ws, size_t ws_size,
                              hipStream_t stream) {
    const float* x     = (const float*)d_in[0];
    const int*   ei    = (const int*)d_in[1];
    const int*   batch = (const int*)d_in[3];
    const float* Wl1 = (const float*)d_in[4],  *bl1 = (const float*)d_in[5];
    const float* Wr1 = (const float*)d_in[6],  *br1 = (const float*)d_in[7];
    const float* att1= (const float*)d_in[8],  *b1  = (const float*)d_in[9];
    const float* Wl2 = (const float*)d_in[10], *bl2 = (const float*)d_in[11];
    const float* Wr2 = (const float*)d_in[12], *br2 = (const float*)d_in[13];
    const float* att2= (const float*)d_in[14], *b2  = (const float*)d_in[15];
    const float* Wlin= (const float*)d_in[16], *blin= (const float*)d_in[17];
    float* out = (float*)d_out;

    const int* src = ei;             // edge_index[0]
    const int* dst = ei + N_EDGES;   // edge_index[1]

    char* p = (char*)d_ws;
    auto carve = [&](size_t bytes) {
        void* r = (void*)p;
        p += (bytes + 255) & ~(size_t)255;
        return r;
    };
    float* bufA    = (float*)carve((size_t)N_NODES * 128 * 4);
    float* bufB    = (float*)carve((size_t)N_NODES * 128 * 4);
    float* bufC    = (float*)carve((size_t)N_NODES * 128 * 4);
    int*   offsets = (int*)carve((size_t)(N_NODES + 1) * 4);
    int*   cursor  = (int*)carve((size_t)N_NODES * 4);
    int*   col_src = (int*)carve((size_t)N_EDGES * 4);
    // zero-initialized region (one memset): counts | status | psum | pcnt | done
    char* zb = (char*)carve(200192 + 1024 + 262144 + 2048 + 256);
    int*          counts = (int*)zb;
    unsigned int* status = (unsigned int*)(zb + 200192);
    float*        psum   = (float*)(zb + 200192 + 1024);
    float*        pcnt   = (float*)(zb + 200192 + 1024 + 262144);
    int*          done   = (int*)(zb + 200192 + 1024 + 262144 + 2048);
    const size_t zbytes  = 200192 + 1024 + 262144 + 2048 + 256;

    hipMemsetAsync(zb, 0, zbytes, stream);

    k_hist<<<(N_EDGES + 255) / 256, 256, 0, stream>>>(dst, counts);
    k_scan<<<SCAN_NB, 256, 0, stream>>>(counts, offsets, cursor, status);
    k_fill<<<(N_EDGES + 255) / 256, 256, 0, stream>>>(src, dst, cursor, col_src);

    dim3 gg((N_NODES + 127) / 128, 2);
    // layer 1
    k_gemm_dual<<<gg, 256, 0, stream>>>(x, Wl1, bl1, Wr1, br1, bufA, bufB, F_IN);
    k_edge<<<N_NODES / 2, 256, 0, stream>>>(bufA, bufB, att1, b1, offsets, col_src, bufC);
    // layer 2
    k_gemm_dual<<<gg, 256, 0, stream>>>(bufC, Wl2, bl2, Wr2, br2, bufA, bufB, H_DIM);
    k_edge<<<N_NODES / 2, 256, 0, stream>>>(bufA, bufB, att2, b2, offsets, col_src, bufC);
    // pool + head (fused)
    k_pool_head<<<(N_NODES + 127) / 128, 128, 0, stream>>>(
        bufC, batch, psum, pcnt, done, Wlin, blin, out);
}

// Round 7
// 446.008 us; speedup vs baseline: 1.0704x; 1.0704x over previous
//
#include <hip/hip_runtime.h>
#include <math.h>

#define N_NODES 50000
#define N_EDGES 800000
#define F_IN    64
#define H_DIM   128
#define N_GRAPH 512
#define NEG_SLOPE 0.2f

typedef __attribute__((ext_vector_type(8))) short short8;   // 8 bf16 (4 VGPRs)
typedef __attribute__((ext_vector_type(4))) float f32x4;

// fp32 -> bf16(hi) + bf16(lo), truncation split (residual ~2^-16 relative)
__device__ __forceinline__ void bsplit(float v, unsigned short& h, unsigned short& l) {
    unsigned u = __float_as_uint(v);
    h = (unsigned short)(u >> 16);
    float hf = __uint_as_float(u & 0xFFFF0000u);
    float r = v - hf;
    l = (unsigned short)(__float_as_uint(r) >> 16);
}
__device__ __forceinline__ float bjoin(unsigned short h, unsigned short l) {
    return __uint_as_float(((unsigned)h) << 16) + __uint_as_float(((unsigned)l) << 16);
}

// ---------------------------------------------------------------- CSR build
__global__ __launch_bounds__(256) void k_hist(const int* __restrict__ dst,
                                              int* __restrict__ counts) {
    int e = blockIdx.x * 256 + threadIdx.x;
    if (e < N_EDGES) atomicAdd(&counts[dst[e]], 1);
}

__global__ __launch_bounds__(256) void k_scan1(const int* __restrict__ counts,
                                               int* __restrict__ excl,
                                               int* __restrict__ partials) {
    __shared__ int s[256];
    int t = threadIdx.x, gid = blockIdx.x * 256 + t;
    int v = (gid < N_NODES) ? counts[gid] : 0;
    s[t] = v;
    __syncthreads();
    for (int off = 1; off < 256; off <<= 1) {
        int x = (t >= off) ? s[t - off] : 0;
        __syncthreads();
        s[t] += x;
        __syncthreads();
    }
    if (gid < N_NODES) excl[gid] = s[t] - v;
    if (t == 255) partials[blockIdx.x] = s[t];
}

__global__ __launch_bounds__(256) void k_scan2(int* __restrict__ partials, int nb) {
    __shared__ int s[256];
    int t = threadIdx.x;
    int v = (t < nb) ? partials[t] : 0;
    s[t] = v;
    __syncthreads();
    for (int off = 1; off < 256; off <<= 1) {
        int x = (t >= off) ? s[t - off] : 0;
        __syncthreads();
        s[t] += x;
        __syncthreads();
    }
    if (t < nb) partials[t] = s[t] - v;
}

__global__ __launch_bounds__(256) void k_scan3(int* __restrict__ offsets,
                                               const int* __restrict__ partials,
                                               int* __restrict__ cursor) {
    int gid = blockIdx.x * 256 + threadIdx.x;
    if (gid < N_NODES) {
        int v = offsets[gid] + partials[blockIdx.x];
        offsets[gid] = v;
        cursor[gid]  = v;
    }
    if (gid == 0) offsets[N_NODES] = N_EDGES;
}

__global__ __launch_bounds__(256) void k_fill(const int* __restrict__ src,
                                              const int* __restrict__ dst,
                                              int* __restrict__ cursor,
                                              int* __restrict__ col_src) {
    int e = blockIdx.x * 256 + threadIdx.x;
    if (e < N_EDGES) {
        int pos = atomicAdd(&cursor[dst[e]], 1);
        col_src[pos] = src[e];
    }
}

// ---------------------------------------------------------------- bf16 prep
__global__ __launch_bounds__(256) void k_prepX(const float* __restrict__ x,
                                               unsigned short* __restrict__ hi,
                                               unsigned short* __restrict__ lo) {
    int i4 = (blockIdx.x * 256 + threadIdx.x) * 4;
    if (i4 >= N_NODES * F_IN) return;
    float4 v = *(const float4*)(x + i4);
    ushort4 h, l;
    bsplit(v.x, h.x, l.x); bsplit(v.y, h.y, l.y);
    bsplit(v.z, h.z, l.z); bsplit(v.w, h.w, l.w);
    *(ushort4*)(hi + i4) = h;
    *(ushort4*)(lo + i4) = l;
}

// All four W matrices -> transposed bf16 hi/lo: WT[c][k] per matrix.
// Layout: [Wl1(128x64) | Wr1(128x64) | Wl2(128x128) | Wr2(128x128)]
__global__ __launch_bounds__(256) void k_prepW(
    const float* __restrict__ Wl1, const float* __restrict__ Wr1,
    const float* __restrict__ Wl2, const float* __restrict__ Wr2,
    unsigned short* __restrict__ hi, unsigned short* __restrict__ lo) {
    int idx = blockIdx.x * 256 + threadIdx.x;   // 0..49151
    if (idx >= 49152) return;
    const float* W; int K, li;
    if (idx < 8192)       { W = Wl1; K = 64;  li = idx; }
    else if (idx < 16384) { W = Wr1; K = 64;  li = idx - 8192; }
    else if (idx < 32768) { W = Wl2; K = 128; li = idx - 16384; }
    else                  { W = Wr2; K = 128; li = idx - 32768; }
    int c = li / K, k = li - c * K;
    unsigned short h, l;
    bsplit(W[k * 128 + c], h, l);
    hi[idx] = h; lo[idx] = l;
}

// ---------------------------------------------------------------- MFMA GEMM
// OL = X@Wl + bl, OR = X@Wr + br via 3-pass bf16-split MFMA (16x16x32).
// Block: 64 rows x 128 cols x both outputs; 4 waves, wave w owns cols [w*32,+32).
// WT layout: [o][c][K] bf16 (k-contig). X hi/lo: [N][K] bf16.
#define APITCH 40   // bf16 units per LDS A row (32 + pad, keeps 16B align)
#define WPITCH 40
__global__ __launch_bounds__(256, 3) void k_gemm_mfma(
    const unsigned short* __restrict__ Xhi, const unsigned short* __restrict__ Xlo,
    const unsigned short* __restrict__ WThi, const unsigned short* __restrict__ WTlo,
    const float* __restrict__ bl, const float* __restrict__ br,
    float* __restrict__ OL, float* __restrict__ OR_, int K)
{
    __shared__ __align__(16) unsigned short Ah[64 * APITCH];
    __shared__ __align__(16) unsigned short Al[64 * APITCH];
    __shared__ __align__(16) unsigned short Wh[2 * 128 * WPITCH];
    __shared__ __align__(16) unsigned short Wl_[2 * 128 * WPITCH];

    const int tid  = threadIdx.x;
    const int wv   = tid >> 6;        // wave: cols [wv*32, wv*32+32)
    const int lane = tid & 63;
    const int n16  = lane & 15;
    const int quad = lane >> 4;
    const int row0 = blockIdx.x * 64;

    f32x4 acc[4][2][2];               // [rtile][ctile][out]
#pragma unroll
    for (int r = 0; r < 4; ++r)
#pragma unroll
        for (int c = 0; c < 2; ++c)
#pragma unroll
            for (int o = 0; o < 2; ++o) acc[r][c][o] = (f32x4)0.f;

    for (int kk = 0; kk < K; kk += 32) {
        // stage X tile: 64 rows x 32 k, hi+lo. 512 chunks of 16B.
#pragma unroll
        for (int jj = 0; jj < 2; ++jj) {
            int j = tid + jj * 256;              // 0..511
            int part = j >> 8;                   // 0=hi 1=lo
            int r = (j & 255) >> 2, sub = j & 3;
            int grow = row0 + r;
            const unsigned short* s = (part ? Xlo : Xhi) + (size_t)grow * K + kk + sub * 8;
            unsigned short* dl = (part ? Al : Ah) + r * APITCH + sub * 8;
            uint4 v = make_uint4(0u, 0u, 0u, 0u);
            if (grow < N_NODES) v = *(const uint4*)s;
            *(uint4*)dl = v;
        }
        // stage W tiles: 2 parts x (2 outs x 128 cols) x 32 k. 2048 chunks of 16B.
#pragma unroll
        for (int jj = 0; jj < 8; ++jj) {
            int j = tid + jj * 256;              // 0..2047
            int part = j >> 10;                  // 0=hi 1=lo
            int oc = (j & 1023) >> 2;            // 0..255 = o*128+col
            int sub = j & 3;
            const unsigned short* s = (part ? WTlo : WThi) + (size_t)oc * K + kk + sub * 8;
            unsigned short* dl = (part ? Wl_ : Wh) + oc * WPITCH + sub * 8;
            *(uint4*)dl = *(const uint4*)s;
        }
        __syncthreads();

        short8 bh[2][2], bo[2][2];
#pragma unroll
        for (int c = 0; c < 2; ++c)
#pragma unroll
            for (int o = 0; o < 2; ++o) {
                int col = wv * 32 + c * 16 + n16;
                bh[c][o] = *(const short8*)(Wh  + (o * 128 + col) * WPITCH + quad * 8);
                bo[c][o] = *(const short8*)(Wl_ + (o * 128 + col) * WPITCH + quad * 8);
            }
#pragma unroll
        for (int r = 0; r < 4; ++r) {
            int rl = r * 16 + n16;
            short8 ah = *(const short8*)(Ah + rl * APITCH + quad * 8);
            short8 al = *(const short8*)(Al + rl * APITCH + quad * 8);
#pragma unroll
            for (int c = 0; c < 2; ++c)
#pragma unroll
                for (int o = 0; o < 2; ++o) {
                    f32x4 t = acc[r][c][o];
                    t = __builtin_amdgcn_mfma_f32_16x16x32_bf16(ah, bh[c][o], t, 0, 0, 0);
                    t = __builtin_amdgcn_mfma_f32_16x16x32_bf16(ah, bo[c][o], t, 0, 0, 0);
                    t = __builtin_amdgcn_mfma_f32_16x16x32_bf16(al, bh[c][o], t, 0, 0, 0);
                    acc[r][c][o] = t;
                }
        }
        __syncthreads();
    }

    // epilogue: C/D layout col=lane&15, row=quad*4+reg
#pragma unroll
    for (int r = 0; r < 4; ++r)
#pragma unroll
        for (int c = 0; c < 2; ++c)
#pragma unroll
            for (int o = 0; o < 2; ++o) {
                int col = wv * 32 + c * 16 + n16;
                float bb = (o ? br : bl)[col];
                float* O = o ? OR_ : OL;
#pragma unroll
                for (int g = 0; g < 4; ++g) {
                    int grow = row0 + r * 16 + quad * 4 + g;
                    if (grow < N_NODES)
                        O[(size_t)grow * 128 + col] = acc[r][c][o][g] + bb;
                }
            }
}

// ---------------------------------------------------------------- edge phase
__device__ __forceinline__ float dot8_leaky(const float4& x0, const float4& x1,
                                            const float4& r0, const float4& r1,
                                            const float4& a0, const float4& a1) {
    float s = 0.f, e;
    e = x0.x + r0.x; s = fmaf(a0.x, (e > 0.f ? e : NEG_SLOPE * e), s);
    e = x0.y + r0.y; s = fmaf(a0.y, (e > 0.f ? e : NEG_SLOPE * e), s);
    e = x0.z + r0.z; s = fmaf(a0.z, (e > 0.f ? e : NEG_SLOPE * e), s);
    e = x0.w + r0.w; s = fmaf(a0.w, (e > 0.f ? e : NEG_SLOPE * e), s);
    e = x1.x + r1.x; s = fmaf(a1.x, (e > 0.f ? e : NEG_SLOPE * e), s);
    e = x1.y + r1.y; s = fmaf(a1.y, (e > 0.f ? e : NEG_SLOPE * e), s);
    e = x1.z + r1.z; s = fmaf(a1.z, (e > 0.f ? e : NEG_SLOPE * e), s);
    e = x1.w + r1.w; s = fmaf(a1.w, (e > 0.f ? e : NEG_SLOPE * e), s);
    return s;
}

// One wave per destination node; 4 quarters of 16 lanes each process a
// different incoming edge (R2-proven structure). BF16OUT writes hi/lo bf16.
template<bool BF16OUT>
__global__ __launch_bounds__(256) void k_edge(
    const float* __restrict__ xl, const float* __restrict__ xr,
    const float* __restrict__ att, const float* __restrict__ bias,
    const int* __restrict__ offsets, const int* __restrict__ col_src,
    float* __restrict__ outF,
    unsigned short* __restrict__ outHi, unsigned short* __restrict__ outLo)
{
    int d = blockIdx.x * 4 + (threadIdx.x >> 6);
    if (d >= N_NODES) return;
    const int lane = threadIdx.x & 63;
    const int q = lane >> 4;
    const int t = lane & 15;
    const size_t dim0 = (size_t)t * 8;

    const float4 r0 = *(const float4*)(xr + (size_t)d * 128 + dim0);
    const float4 r1 = *(const float4*)(xr + (size_t)d * 128 + dim0 + 4);
    const float4 a0 = *(const float4*)(att + dim0);
    const float4 a1 = *(const float4*)(att + dim0 + 4);

    const float4 xs0 = *(const float4*)(xl + (size_t)d * 128 + dim0);
    const float4 xs1 = *(const float4*)(xl + (size_t)d * 128 + dim0 + 4);
    float sl = dot8_leaky(xs0, xs1, r0, r1, a0, a1);
#pragma unroll
    for (int off = 1; off < 16; off <<= 1) sl += __shfl_xor(sl, off);

    float m, lsum;
    float4 acc0, acc1;
    if (q == 0) {
        m = sl; lsum = 1.f; acc0 = xs0; acc1 = xs1;
    } else {
        m = -INFINITY; lsum = 0.f;
        acc0 = make_float4(0.f, 0.f, 0.f, 0.f);
        acc1 = make_float4(0.f, 0.f, 0.f, 0.f);
    }

    const int ibeg = offsets[d], iend = offsets[d + 1];
    for (int base = ibeg; base < iend; base += 4) {
        int i = base + q;
        bool valid = (i < iend);
        int s = valid ? col_src[i] : d;
        const float4 x0 = *(const float4*)(xl + (size_t)s * 128 + dim0);
        const float4 x1 = *(const float4*)(xl + (size_t)s * 128 + dim0 + 4);
        float logit = dot8_leaky(x0, x1, r0, r1, a0, a1);
#pragma unroll
        for (int off = 1; off < 16; off <<= 1) logit += __shfl_xor(logit, off);
        if (valid) {
            float nm = fmaxf(m, logit);
            float sc = __expf(m - nm);
            float w  = __expf(logit - nm);
            lsum = lsum * sc + w;
            acc0.x = acc0.x * sc + w * x0.x;
            acc0.y = acc0.y * sc + w * x0.y;
            acc0.z = acc0.z * sc + w * x0.z;
            acc0.w = acc0.w * sc + w * x0.w;
            acc1.x = acc1.x * sc + w * x1.x;
            acc1.y = acc1.y * sc + w * x1.y;
            acc1.z = acc1.z * sc + w * x1.z;
            acc1.w = acc1.w * sc + w * x1.w;
            m = nm;
        }
    }

    float M = m;
    M = fmaxf(M, __shfl_xor(M, 16));
    M = fmaxf(M, __shfl_xor(M, 32));
    float sc = __expf(m - M);
    lsum *= sc;
    acc0.x *= sc; acc0.y *= sc; acc0.z *= sc; acc0.w *= sc;
    acc1.x *= sc; acc1.y *= sc; acc1.z *= sc; acc1.w *= sc;
#pragma unroll
    for (int off = 16; off <= 32; off <<= 1) {
        lsum  += __shfl_xor(lsum, off);
        acc0.x += __shfl_xor(acc0.x, off);
        acc0.y += __shfl_xor(acc0.y, off);
        acc0.z += __shfl_xor(acc0.z, off);
        acc0.w += __shfl_xor(acc0.w, off);
        acc1.x += __shfl_xor(acc1.x, off);
        acc1.y += __shfl_xor(acc1.y, off);
        acc1.z += __shfl_xor(acc1.z, off);
        acc1.w += __shfl_xor(acc1.w, off);
    }

    if (q == 0) {
        float inv = 1.f / lsum;
        const float4 b0 = *(const float4*)(bias + dim0);
        const float4 b1 = *(const float4*)(bias + dim0 + 4);
        float v[8];
        v[0] = fmaxf(fmaf(acc0.x, inv, b0.x), 0.f);
        v[1] = fmaxf(fmaf(acc0.y, inv, b0.y), 0.f);
        v[2] = fmaxf(fmaf(acc0.z, inv, b0.z), 0.f);
        v[3] = fmaxf(fmaf(acc0.w, inv, b0.w), 0.f);
        v[4] = fmaxf(fmaf(acc1.x, inv, b1.x), 0.f);
        v[5] = fmaxf(fmaf(acc1.y, inv, b1.y), 0.f);
        v[6] = fmaxf(fmaf(acc1.z, inv, b1.z), 0.f);
        v[7] = fmaxf(fmaf(acc1.w, inv, b1.w), 0.f);
        if constexpr (BF16OUT) {
            union { unsigned short s[8]; uint4 u; } H, L;
#pragma unroll
            for (int i = 0; i < 8; ++i) bsplit(v[i], H.s[i], L.s[i]);
            *(uint4*)(outHi + (size_t)d * 128 + dim0) = H.u;
            *(uint4*)(outLo + (size_t)d * 128 + dim0) = L.u;
        } else {
            *(float4*)(outF + (size_t)d * 128 + dim0) =
                make_float4(v[0], v[1], v[2], v[3]);
            *(float4*)(outF + (size_t)d * 128 + dim0 + 4) =
                make_float4(v[4], v[5], v[6], v[7]);
        }
    }
}

// ---------------------------------------------------------------- pool+head
__global__ __launch_bounds__(128) void k_pool_head(
    const unsigned short* __restrict__ hHi, const unsigned short* __restrict__ hLo,
    const int* __restrict__ batch,
    float* __restrict__ psum, float* __restrict__ pcnt,
    int* __restrict__ done,
    const float* __restrict__ Wlin, const float* __restrict__ blin,
    float* __restrict__ out)
{
    int dim = threadIdx.x;
    int n0 = blockIdx.x * 128;
    int nend = n0 + 128; if (nend > N_NODES) nend = N_NODES;
    float accv = 0.f;
    int cur = -1, crun = 0;
    for (int n = n0; n < nend; ++n) {
        int g = batch[n];
        if (g != cur) {
            if (cur >= 0) {
                atomicAdd(&psum[cur * 128 + dim], accv);
                if (dim == 0) atomicAdd(&pcnt[cur], (float)crun);
            }
            cur = g; accv = 0.f; crun = 0;
        }
        accv += bjoin(hHi[(size_t)n * 128 + dim], hLo[(size_t)n * 128 + dim]);
        crun++;
    }
    if (cur >= 0) {
        atomicAdd(&psum[cur * 128 + dim], accv);
        if (dim == 0) atomicAdd(&pcnt[cur], (float)crun);
    }

    __threadfence();
    __shared__ int lastFlag;
    if (threadIdx.x == 0) {
        int dn = atomicAdd(done, 1);
        lastFlag = (dn == (int)gridDim.x - 1);
    }
    __syncthreads();
    if (lastFlag) {
        __threadfence();
        for (int g = threadIdx.x; g < N_GRAPH; g += 128) {
            float c = fmaxf(pcnt[g], 1.f);
            float acc = 0.f;
#pragma unroll 8
            for (int k = 0; k < 128; ++k)
                acc = fmaf(psum[g * 128 + k], Wlin[k], acc);
            out[g] = acc / c + blin[0];
        }
    }
}

// ---------------------------------------------------------------- launch
extern "C" void kernel_launch(void* const* d_in, const int* in_sizes, int n_in,
                              void* d_out, int out_size, void* d_ws, size_t ws_size,
                              hipStream_t stream) {
    const float* x     = (const float*)d_in[0];
    const int*   ei    = (const int*)d_in[1];
    const int*   batch = (const int*)d_in[3];
    const float* Wl1 = (const float*)d_in[4],  *bl1 = (const float*)d_in[5];
    const float* Wr1 = (const float*)d_in[6],  *br1 = (const float*)d_in[7];
    const float* att1= (const float*)d_in[8],  *b1  = (const float*)d_in[9];
    const float* Wl2 = (const float*)d_in[10], *bl2 = (const float*)d_in[11];
    const float* Wr2 = (const float*)d_in[12], *br2 = (const float*)d_in[13];
    const float* att2= (const float*)d_in[14], *b2  = (const float*)d_in[15];
    const float* Wlin= (const float*)d_in[16], *blin= (const float*)d_in[17];
    float* out = (float*)d_out;

    const int* src = ei;
    const int* dst = ei + N_EDGES;

    char* p = (char*)d_ws;
    auto carve = [&](size_t bytes) {
        void* r = (void*)p;
        p += (bytes + 255) & ~(size_t)255;
        return r;
    };
    float*          bufA   = (float*)carve((size_t)N_NODES * 128 * 4);          // xl fp32
    float*          bufB   = (float*)carve((size_t)N_NODES * 128 * 4);          // xr fp32
    unsigned short* Hhi    = (unsigned short*)carve((size_t)N_NODES * 128 * 2); // h bf16 hi
    unsigned short* Hlo    = (unsigned short*)carve((size_t)N_NODES * 128 * 2); // h bf16 lo
    unsigned short* Xhi1   = (unsigned short*)carve((size_t)N_NODES * 64 * 2);
    unsigned short* Xlo1   = (unsigned short*)carve((size_t)N_NODES * 64 * 2);
    unsigned short* WThi   = (unsigned short*)carve(49152 * 2);
    unsigned short* WTlo   = (unsigned short*)carve(49152 * 2);
    int*            offsets= (int*)carve((size_t)(N_NODES + 1) * 4);
    int*            cursor = (int*)carve((size_t)N_NODES * 4);
    int*            partials=(int*)carve(256 * 4);
    int*            col_src= (int*)carve((size_t)N_EDGES * 4);
    // zero region: counts | psum | pcnt | done
    char* zb = (char*)carve(200192 + 262144 + 2048 + 256);
    int*   counts = (int*)zb;
    float* psum   = (float*)(zb + 200192);
    float* pcnt   = (float*)(zb + 200192 + 262144);
    int*   done   = (int*)(zb + 200192 + 262144 + 2048);
    const size_t zbytes = 200192 + 262144 + 2048 + 256;

    hipMemsetAsync(zb, 0, zbytes, stream);

    const int NB1 = (N_NODES + 255) / 256;   // 196
    k_hist <<<(N_EDGES + 255) / 256, 256, 0, stream>>>(dst, counts);
    k_scan1<<<NB1, 256, 0, stream>>>(counts, offsets, partials);
    k_scan2<<<1, 256, 0, stream>>>(partials, NB1);
    k_scan3<<<NB1, 256, 0, stream>>>(offsets, partials, cursor);
    k_fill <<<(N_EDGES + 255) / 256, 256, 0, stream>>>(src, dst, cursor, col_src);

    k_prepW<<<192, 256, 0, stream>>>(Wl1, Wr1, Wl2, Wr2, WThi, WTlo);
    k_prepX<<<(N_NODES * 64 / 4 + 255) / 256, 256, 0, stream>>>(x, Xhi1, Xlo1);

    const int GB = (N_NODES + 63) / 64;      // 782
    // layer 1 (K=64): WT offset 0
    k_gemm_mfma<<<GB, 256, 0, stream>>>(Xhi1, Xlo1, WThi, WTlo,
                                        bl1, br1, bufA, bufB, F_IN);
    k_edge<true><<<(N_NODES + 3) / 4, 256, 0, stream>>>(
        bufA, bufB, att1, b1, offsets, col_src, nullptr, Hhi, Hlo);
    // layer 2 (K=128): WT offset 16384
    k_gemm_mfma<<<GB, 256, 0, stream>>>(Hhi, Hlo, WThi + 16384, WTlo + 16384,
                                        bl2, br2, bufA, bufB, H_DIM);
    k_edge<true><<<(N_NODES + 3) / 4, 256, 0, stream>>>(
        bufA, bufB, att2, b2, offsets, col_src, nullptr, Hhi, Hlo);
    // pool + head
    k_pool_head<<<(N_NODES + 127) / 128, 128, 0, stream>>>(
        Hhi, Hlo, batch, psum, pcnt, done, Wlin, blin, out);
}

// Round 8
// 410.797 us; speedup vs baseline: 1.1621x; 1.0857x over previous
//
#include <hip/hip_runtime.h>
#include <math.h>

#define N_NODES 50000
#define N_EDGES 800000
#define F_IN    64
#define H_DIM   128
#define N_GRAPH 512
#define NEG_SLOPE 0.2f

typedef __attribute__((ext_vector_type(8))) short short8;   // 8 bf16 (4 VGPRs)
typedef __attribute__((ext_vector_type(4))) float f32x4;

// fp32 -> bf16(hi) + bf16(lo), truncation split (residual ~2^-16 relative)
__device__ __forceinline__ void bsplit(float v, unsigned short& h, unsigned short& l) {
    unsigned u = __float_as_uint(v);
    h = (unsigned short)(u >> 16);
    float hf = __uint_as_float(u & 0xFFFF0000u);
    float r = v - hf;
    l = (unsigned short)(__float_as_uint(r) >> 16);
}
__device__ __forceinline__ float bjoin(unsigned short h, unsigned short l) {
    return __uint_as_float(((unsigned)h) << 16) + __uint_as_float(((unsigned)l) << 16);
}

// ---------------------------------------------------------------- CSR build
__global__ __launch_bounds__(256) void k_hist(const int* __restrict__ dst,
                                              int* __restrict__ counts) {
    int e = blockIdx.x * 256 + threadIdx.x;
    if (e < N_EDGES) atomicAdd(&counts[dst[e]], 1);
}

__global__ __launch_bounds__(256) void k_scan1(const int* __restrict__ counts,
                                               int* __restrict__ excl,
                                               int* __restrict__ partials) {
    __shared__ int s[256];
    int t = threadIdx.x, gid = blockIdx.x * 256 + t;
    int v = (gid < N_NODES) ? counts[gid] : 0;
    s[t] = v;
    __syncthreads();
    for (int off = 1; off < 256; off <<= 1) {
        int x = (t >= off) ? s[t - off] : 0;
        __syncthreads();
        s[t] += x;
        __syncthreads();
    }
    if (gid < N_NODES) excl[gid] = s[t] - v;
    if (t == 255) partials[blockIdx.x] = s[t];
}

__global__ __launch_bounds__(256) void k_scan2(int* __restrict__ partials, int nb) {
    __shared__ int s[256];
    int t = threadIdx.x;
    int v = (t < nb) ? partials[t] : 0;
    s[t] = v;
    __syncthreads();
    for (int off = 1; off < 256; off <<= 1) {
        int x = (t >= off) ? s[t - off] : 0;
        __syncthreads();
        s[t] += x;
        __syncthreads();
    }
    if (t < nb) partials[t] = s[t] - v;
}

__global__ __launch_bounds__(256) void k_scan3(int* __restrict__ offsets,
                                               const int* __restrict__ partials,
                                               int* __restrict__ cursor) {
    int gid = blockIdx.x * 256 + threadIdx.x;
    if (gid < N_NODES) {
        int v = offsets[gid] + partials[blockIdx.x];
        offsets[gid] = v;
        cursor[gid]  = v;
    }
    if (gid == 0) offsets[N_NODES] = N_EDGES;
}

__global__ __launch_bounds__(256) void k_fill(const int* __restrict__ src,
                                              const int* __restrict__ dst,
                                              int* __restrict__ cursor,
                                              int* __restrict__ col_src) {
    int e = blockIdx.x * 256 + threadIdx.x;
    if (e < N_EDGES) {
        int pos = atomicAdd(&cursor[dst[e]], 1);
        col_src[pos] = src[e];
    }
}

// ---------------------------------------------------------------- bf16 prep
__global__ __launch_bounds__(256) void k_prepX(const float* __restrict__ x,
                                               unsigned short* __restrict__ hi,
                                               unsigned short* __restrict__ lo) {
    int i4 = (blockIdx.x * 256 + threadIdx.x) * 4;
    if (i4 >= N_NODES * F_IN) return;
    float4 v = *(const float4*)(x + i4);
    ushort4 h, l;
    bsplit(v.x, h.x, l.x); bsplit(v.y, h.y, l.y);
    bsplit(v.z, h.z, l.z); bsplit(v.w, h.w, l.w);
    *(ushort4*)(hi + i4) = h;
    *(ushort4*)(lo + i4) = l;
}

// All four W matrices -> transposed bf16 hi/lo: WT[c][k] per matrix.
// Layout: [Wl1(128x64) | Wr1(128x64) | Wl2(128x128) | Wr2(128x128)]
__global__ __launch_bounds__(256) void k_prepW(
    const float* __restrict__ Wl1, const float* __restrict__ Wr1,
    const float* __restrict__ Wl2, const float* __restrict__ Wr2,
    unsigned short* __restrict__ hi, unsigned short* __restrict__ lo) {
    int idx = blockIdx.x * 256 + threadIdx.x;   // 0..49151
    if (idx >= 49152) return;
    const float* W; int K, li;
    if (idx < 8192)       { W = Wl1; K = 64;  li = idx; }
    else if (idx < 16384) { W = Wr1; K = 64;  li = idx - 8192; }
    else if (idx < 32768) { W = Wl2; K = 128; li = idx - 16384; }
    else                  { W = Wr2; K = 128; li = idx - 32768; }
    int c = li / K, k = li - c * K;
    unsigned short h, l;
    bsplit(W[k * 128 + c], h, l);
    hi[idx] = h; lo[idx] = l;
}

// ---------------------------------------------------------------- MFMA GEMM
// OL = X@Wl + bl, OR = X@Wr + br via 3-pass bf16-split MFMA (16x16x32).
#define APITCH 40
#define WPITCH 40
__global__ __launch_bounds__(256, 3) void k_gemm_mfma(
    const unsigned short* __restrict__ Xhi, const unsigned short* __restrict__ Xlo,
    const unsigned short* __restrict__ WThi, const unsigned short* __restrict__ WTlo,
    const float* __restrict__ bl, const float* __restrict__ br,
    float* __restrict__ OL, float* __restrict__ OR_, int K)
{
    __shared__ __align__(16) unsigned short Ah[64 * APITCH];
    __shared__ __align__(16) unsigned short Al[64 * APITCH];
    __shared__ __align__(16) unsigned short Wh[2 * 128 * WPITCH];
    __shared__ __align__(16) unsigned short Wl_[2 * 128 * WPITCH];

    const int tid  = threadIdx.x;
    const int wv   = tid >> 6;
    const int lane = tid & 63;
    const int n16  = lane & 15;
    const int quad = lane >> 4;
    const int row0 = blockIdx.x * 64;

    f32x4 acc[4][2][2];
#pragma unroll
    for (int r = 0; r < 4; ++r)
#pragma unroll
        for (int c = 0; c < 2; ++c)
#pragma unroll
            for (int o = 0; o < 2; ++o) acc[r][c][o] = (f32x4)0.f;

    for (int kk = 0; kk < K; kk += 32) {
        // stage X tile: 64 rows x 32 k, hi+lo. 512 chunks of 16B.
#pragma unroll
        for (int jj = 0; jj < 2; ++jj) {
            int j = tid + jj * 256;
            int part = j >> 8;
            int r = (j & 255) >> 2, sub = j & 3;
            int grow = row0 + r;
            const unsigned short* s = (part ? Xlo : Xhi) + (size_t)grow * K + kk + sub * 8;
            unsigned short* dl = (part ? Al : Ah) + r * APITCH + sub * 8;
            uint4 v = make_uint4(0u, 0u, 0u, 0u);
            if (grow < N_NODES) v = *(const uint4*)s;
            *(uint4*)dl = v;
        }
        // stage W tiles: 2 parts x (2 outs x 128 cols) x 32 k. 2048 chunks.
#pragma unroll
        for (int jj = 0; jj < 8; ++jj) {
            int j = tid + jj * 256;
            int part = j >> 10;
            int oc = (j & 1023) >> 2;
            int sub = j & 3;
            const unsigned short* s = (part ? WTlo : WThi) + (size_t)oc * K + kk + sub * 8;
            unsigned short* dl = (part ? Wl_ : Wh) + oc * WPITCH + sub * 8;
            *(uint4*)dl = *(const uint4*)s;
        }
        __syncthreads();

        short8 bh[2][2], bo[2][2];
#pragma unroll
        for (int c = 0; c < 2; ++c)
#pragma unroll
            for (int o = 0; o < 2; ++o) {
                int col = wv * 32 + c * 16 + n16;
                bh[c][o] = *(const short8*)(Wh  + (o * 128 + col) * WPITCH + quad * 8);
                bo[c][o] = *(const short8*)(Wl_ + (o * 128 + col) * WPITCH + quad * 8);
            }
#pragma unroll
        for (int r = 0; r < 4; ++r) {
            int rl = r * 16 + n16;
            short8 ah = *(const short8*)(Ah + rl * APITCH + quad * 8);
            short8 al = *(const short8*)(Al + rl * APITCH + quad * 8);
#pragma unroll
            for (int c = 0; c < 2; ++c)
#pragma unroll
                for (int o = 0; o < 2; ++o) {
                    f32x4 t = acc[r][c][o];
                    t = __builtin_amdgcn_mfma_f32_16x16x32_bf16(ah, bh[c][o], t, 0, 0, 0);
                    t = __builtin_amdgcn_mfma_f32_16x16x32_bf16(ah, bo[c][o], t, 0, 0, 0);
                    t = __builtin_amdgcn_mfma_f32_16x16x32_bf16(al, bh[c][o], t, 0, 0, 0);
                    acc[r][c][o] = t;
                }
        }
        __syncthreads();
    }

    // epilogue: C/D layout col=lane&15, row=quad*4+reg
#pragma unroll
    for (int r = 0; r < 4; ++r)
#pragma unroll
        for (int c = 0; c < 2; ++c)
#pragma unroll
            for (int o = 0; o < 2; ++o) {
                int col = wv * 32 + c * 16 + n16;
                float bb = (o ? br : bl)[col];
                float* O = o ? OR_ : OL;
#pragma unroll
                for (int g = 0; g < 4; ++g) {
                    int grow = row0 + r * 16 + quad * 4 + g;
                    if (grow < N_NODES)
                        O[(size_t)grow * 128 + col] = acc[r][c][o][g] + bb;
                }
            }
}

// ---------------------------------------------------------------- edge phase
__device__ __forceinline__ float dot8_leaky(const float4& x0, const float4& x1,
                                            const float4& r0, const float4& r1,
                                            const float4& a0, const float4& a1) {
    float s = 0.f, e;
    e = x0.x + r0.x; s = fmaf(a0.x, (e > 0.f ? e : NEG_SLOPE * e), s);
    e = x0.y + r0.y; s = fmaf(a0.y, (e > 0.f ? e : NEG_SLOPE * e), s);
    e = x0.z + r0.z; s = fmaf(a0.z, (e > 0.f ? e : NEG_SLOPE * e), s);
    e = x0.w + r0.w; s = fmaf(a0.w, (e > 0.f ? e : NEG_SLOPE * e), s);
    e = x1.x + r1.x; s = fmaf(a1.x, (e > 0.f ? e : NEG_SLOPE * e), s);
    e = x1.y + r1.y; s = fmaf(a1.y, (e > 0.f ? e : NEG_SLOPE * e), s);
    e = x1.z + r1.z; s = fmaf(a1.z, (e > 0.f ? e : NEG_SLOPE * e), s);
    e = x1.w + r1.w; s = fmaf(a1.w, (e > 0.f ? e : NEG_SLOPE * e), s);
    return s;
}

// One wave per destination node; 4 quarters of 16 lanes each process a
// different incoming edge (R2-proven structure). BF16OUT writes hi/lo bf16.
template<bool BF16OUT>
__global__ __launch_bounds__(256) void k_edge(
    const float* __restrict__ xl, const float* __restrict__ xr,
    const float* __restrict__ att, const float* __restrict__ bias,
    const int* __restrict__ offsets, const int* __restrict__ col_src,
    float* __restrict__ outF,
    unsigned short* __restrict__ outHi, unsigned short* __restrict__ outLo)
{
    int d = blockIdx.x * 4 + (threadIdx.x >> 6);
    if (d >= N_NODES) return;
    const int lane = threadIdx.x & 63;
    const int q = lane >> 4;
    const int t = lane & 15;
    const size_t dim0 = (size_t)t * 8;

    const float4 r0 = *(const float4*)(xr + (size_t)d * 128 + dim0);
    const float4 r1 = *(const float4*)(xr + (size_t)d * 128 + dim0 + 4);
    const float4 a0 = *(const float4*)(att + dim0);
    const float4 a1 = *(const float4*)(att + dim0 + 4);

    const float4 xs0 = *(const float4*)(xl + (size_t)d * 128 + dim0);
    const float4 xs1 = *(const float4*)(xl + (size_t)d * 128 + dim0 + 4);
    float sl = dot8_leaky(xs0, xs1, r0, r1, a0, a1);
#pragma unroll
    for (int off = 1; off < 16; off <<= 1) sl += __shfl_xor(sl, off);

    float m, lsum;
    float4 acc0, acc1;
    if (q == 0) {
        m = sl; lsum = 1.f; acc0 = xs0; acc1 = xs1;
    } else {
        m = -INFINITY; lsum = 0.f;
        acc0 = make_float4(0.f, 0.f, 0.f, 0.f);
        acc1 = make_float4(0.f, 0.f, 0.f, 0.f);
    }

    const int ibeg = offsets[d], iend = offsets[d + 1];
    for (int base = ibeg; base < iend; base += 4) {
        int i = base + q;
        bool valid = (i < iend);
        int s = valid ? col_src[i] : d;
        const float4 x0 = *(const float4*)(xl + (size_t)s * 128 + dim0);
        const float4 x1 = *(const float4*)(xl + (size_t)s * 128 + dim0 + 4);
        float logit = dot8_leaky(x0, x1, r0, r1, a0, a1);
#pragma unroll
        for (int off = 1; off < 16; off <<= 1) logit += __shfl_xor(logit, off);
        if (valid) {
            float nm = fmaxf(m, logit);
            float sc = __expf(m - nm);
            float w  = __expf(logit - nm);
            lsum = lsum * sc + w;
            acc0.x = acc0.x * sc + w * x0.x;
            acc0.y = acc0.y * sc + w * x0.y;
            acc0.z = acc0.z * sc + w * x0.z;
            acc0.w = acc0.w * sc + w * x0.w;
            acc1.x = acc1.x * sc + w * x1.x;
            acc1.y = acc1.y * sc + w * x1.y;
            acc1.z = acc1.z * sc + w * x1.z;
            acc1.w = acc1.w * sc + w * x1.w;
            m = nm;
        }
    }

    float M = m;
    M = fmaxf(M, __shfl_xor(M, 16));
    M = fmaxf(M, __shfl_xor(M, 32));
    float sc = __expf(m - M);
    lsum *= sc;
    acc0.x *= sc; acc0.y *= sc; acc0.z *= sc; acc0.w *= sc;
    acc1.x *= sc; acc1.y *= sc; acc1.z *= sc; acc1.w *= sc;
#pragma unroll
    for (int off = 16; off <= 32; off <<= 1) {
        lsum  += __shfl_xor(lsum, off);
        acc0.x += __shfl_xor(acc0.x, off);
        acc0.y += __shfl_xor(acc0.y, off);
        acc0.z += __shfl_xor(acc0.z, off);
        acc0.w += __shfl_xor(acc0.w, off);
        acc1.x += __shfl_xor(acc1.x, off);
        acc1.y += __shfl_xor(acc1.y, off);
        acc1.z += __shfl_xor(acc1.z, off);
        acc1.w += __shfl_xor(acc1.w, off);
    }

    if (q == 0) {
        float inv = 1.f / lsum;
        const float4 b0 = *(const float4*)(bias + dim0);
        const float4 b1 = *(const float4*)(bias + dim0 + 4);
        float v[8];
        v[0] = fmaxf(fmaf(acc0.x, inv, b0.x), 0.f);
        v[1] = fmaxf(fmaf(acc0.y, inv, b0.y), 0.f);
        v[2] = fmaxf(fmaf(acc0.z, inv, b0.z), 0.f);
        v[3] = fmaxf(fmaf(acc0.w, inv, b0.w), 0.f);
        v[4] = fmaxf(fmaf(acc1.x, inv, b1.x), 0.f);
        v[5] = fmaxf(fmaf(acc1.y, inv, b1.y), 0.f);
        v[6] = fmaxf(fmaf(acc1.z, inv, b1.z), 0.f);
        v[7] = fmaxf(fmaf(acc1.w, inv, b1.w), 0.f);
        if constexpr (BF16OUT) {
            union { unsigned short s[8]; uint4 u; } H, L;
#pragma unroll
            for (int i = 0; i < 8; ++i) bsplit(v[i], H.s[i], L.s[i]);
            *(uint4*)(outHi + (size_t)d * 128 + dim0) = H.u;
            *(uint4*)(outLo + (size_t)d * 128 + dim0) = L.u;
        } else {
            *(float4*)(outF + (size_t)d * 128 + dim0) =
                make_float4(v[0], v[1], v[2], v[3]);
            *(float4*)(outF + (size_t)d * 128 + dim0 + 4) =
                make_float4(v[4], v[5], v[6], v[7]);
        }
    }
}

// ---------------------------------------------------------------- pooling
// Block = 256 threads = 8 node-rows (ty) x 32 dim-groups (tx, 4 dims each).
// Block covers 64 sorted nodes -> serial depth 8 per thread. Run-length
// accumulation per (ty, tx); flush = 4 float atomics on graph transition.
__global__ __launch_bounds__(256) void k_pool(
    const unsigned short* __restrict__ hHi, const unsigned short* __restrict__ hLo,
    const int* __restrict__ batch,
    float* __restrict__ psum, float* __restrict__ pcnt)
{
    const int tid = threadIdx.x;
    const int tx = tid & 31;        // dims [tx*4, tx*4+4)
    const int ty = tid >> 5;        // row 0..7
    const int n0 = blockIdx.x * 64;
    const int d0 = tx * 4;

    float4 acc = make_float4(0.f, 0.f, 0.f, 0.f);
    int cur = -1, crun = 0;
#pragma unroll
    for (int it = 0; it < 8; ++it) {
        int n = n0 + it * 8 + ty;
        if (n < N_NODES) {
            int g = batch[n];
            if (g != cur) {
                if (cur >= 0) {
                    atomicAdd(&psum[cur * 128 + d0 + 0], acc.x);
                    atomicAdd(&psum[cur * 128 + d0 + 1], acc.y);
                    atomicAdd(&psum[cur * 128 + d0 + 2], acc.z);
                    atomicAdd(&psum[cur * 128 + d0 + 3], acc.w);
                    if (tx == 0) atomicAdd(&pcnt[cur], (float)crun);
                }
                cur = g; acc = make_float4(0.f, 0.f, 0.f, 0.f); crun = 0;
            }
            ushort4 h = *(const ushort4*)(hHi + (size_t)n * 128 + d0);
            ushort4 l = *(const ushort4*)(hLo + (size_t)n * 128 + d0);
            acc.x += bjoin(h.x, l.x);
            acc.y += bjoin(h.y, l.y);
            acc.z += bjoin(h.z, l.z);
            acc.w += bjoin(h.w, l.w);
            crun++;
        }
    }
    if (cur >= 0) {
        atomicAdd(&psum[cur * 128 + d0 + 0], acc.x);
        atomicAdd(&psum[cur * 128 + d0 + 1], acc.y);
        atomicAdd(&psum[cur * 128 + d0 + 2], acc.z);
        atomicAdd(&psum[cur * 128 + d0 + 3], acc.w);
        if (tx == 0) atomicAdd(&pcnt[cur], (float)crun);
    }
}

__global__ __launch_bounds__(256) void k_head(
    const float* __restrict__ psum, const float* __restrict__ pcnt,
    const float* __restrict__ Wlin, const float* __restrict__ blin,
    float* __restrict__ out)
{
    int g = blockIdx.x * 4 + (threadIdx.x >> 6);
    if (g >= N_GRAPH) return;
    int lane = threadIdx.x & 63;
    float c = fmaxf(pcnt[g], 1.f);
    float2 s = *(const float2*)(psum + (size_t)g * 128 + lane * 2);
    float p = (s.x * Wlin[lane * 2] + s.y * Wlin[lane * 2 + 1]) / c;
#pragma unroll
    for (int off = 32; off > 0; off >>= 1) p += __shfl_xor(p, off);
    if (lane == 0) out[g] = p + blin[0];
}

// ---------------------------------------------------------------- launch
extern "C" void kernel_launch(void* const* d_in, const int* in_sizes, int n_in,
                              void* d_out, int out_size, void* d_ws, size_t ws_size,
                              hipStream_t stream) {
    const float* x     = (const float*)d_in[0];
    const int*   ei    = (const int*)d_in[1];
    const int*   batch = (const int*)d_in[3];
    const float* Wl1 = (const float*)d_in[4],  *bl1 = (const float*)d_in[5];
    const float* Wr1 = (const float*)d_in[6],  *br1 = (const float*)d_in[7];
    const float* att1= (const float*)d_in[8],  *b1  = (const float*)d_in[9];
    const float* Wl2 = (const float*)d_in[10], *bl2 = (const float*)d_in[11];
    const float* Wr2 = (const float*)d_in[12], *br2 = (const float*)d_in[13];
    const float* att2= (const float*)d_in[14], *b2  = (const float*)d_in[15];
    const float* Wlin= (const float*)d_in[16], *blin= (const float*)d_in[17];
    float* out = (float*)d_out;

    const int* src = ei;
    const int* dst = ei + N_EDGES;

    char* p = (char*)d_ws;
    auto carve = [&](size_t bytes) {
        void* r = (void*)p;
        p += (bytes + 255) & ~(size_t)255;
        return r;
    };
    float*          bufA   = (float*)carve((size_t)N_NODES * 128 * 4);
    float*          bufB   = (float*)carve((size_t)N_NODES * 128 * 4);
    unsigned short* Hhi    = (unsigned short*)carve((size_t)N_NODES * 128 * 2);
    unsigned short* Hlo    = (unsigned short*)carve((size_t)N_NODES * 128 * 2);
    unsigned short* Xhi1   = (unsigned short*)carve((size_t)N_NODES * 64 * 2);
    unsigned short* Xlo1   = (unsigned short*)carve((size_t)N_NODES * 64 * 2);
    unsigned short* WThi   = (unsigned short*)carve(49152 * 2);
    unsigned short* WTlo   = (unsigned short*)carve(49152 * 2);
    int*            offsets= (int*)carve((size_t)(N_NODES + 1) * 4);
    int*            cursor = (int*)carve((size_t)N_NODES * 4);
    int*            partials=(int*)carve(256 * 4);
    int*            col_src= (int*)carve((size_t)N_EDGES * 4);
    // zero region: counts | psum | pcnt
    char* zb = (char*)carve(200192 + 262144 + 2048);
    int*   counts = (int*)zb;
    float* psum   = (float*)(zb + 200192);
    float* pcnt   = (float*)(zb + 200192 + 262144);
    const size_t zbytes = 200192 + 262144 + 2048;

    hipMemsetAsync(zb, 0, zbytes, stream);

    const int NB1 = (N_NODES + 255) / 256;   // 196
    k_hist <<<(N_EDGES + 255) / 256, 256, 0, stream>>>(dst, counts);
    k_scan1<<<NB1, 256, 0, stream>>>(counts, offsets, partials);
    k_scan2<<<1, 256, 0, stream>>>(partials, NB1);
    k_scan3<<<NB1, 256, 0, stream>>>(offsets, partials, cursor);
    k_fill <<<(N_EDGES + 255) / 256, 256, 0, stream>>>(src, dst, cursor, col_src);

    k_prepW<<<192, 256, 0, stream>>>(Wl1, Wr1, Wl2, Wr2, WThi, WTlo);
    k_prepX<<<(N_NODES * 64 / 4 + 255) / 256, 256, 0, stream>>>(x, Xhi1, Xlo1);

    const int GB = (N_NODES + 63) / 64;      // 782
    // layer 1 (K=64)
    k_gemm_mfma<<<GB, 256, 0, stream>>>(Xhi1, Xlo1, WThi, WTlo,
                                        bl1, br1, bufA, bufB, F_IN);
    k_edge<true><<<(N_NODES + 3) / 4, 256, 0, stream>>>(
        bufA, bufB, att1, b1, offsets, col_src, nullptr, Hhi, Hlo);
    // layer 2 (K=128)
    k_gemm_mfma<<<GB, 256, 0, stream>>>(Hhi, Hlo, WThi + 16384, WTlo + 16384,
                                        bl2, br2, bufA, bufB, H_DIM);
    k_edge<true><<<(N_NODES + 3) / 4, 256, 0, stream>>>(
        bufA, bufB, att2, b2, offsets, col_src, nullptr, Hhi, Hlo);
    // pool + head
    k_pool<<<(N_NODES + 63) / 64, 256, 0, stream>>>(Hhi, Hlo, batch, psum, pcnt);
    k_head<<<(N_GRAPH + 3) / 4, 256, 0, stream>>>(psum, pcnt, Wlin, blin, out);
}